// Round 12
// baseline (148.673 us; speedup 1.0000x reference)
//
#include <hip/hip_runtime.h>

namespace {
constexpr int NA    = 5;
constexpr int NCELL = 361;            // 19*19
constexpr int NBOX  = 1805;           // NA * NCELL
constexpr int KPAD  = 2048;
constexpr int TMAX  = 50;
constexpr float CONF_T = 0.5f;
constexpr float NMS_T  = 0.45f;
constexpr float IOU_T  = 0.5f;
constexpr int NWMAX   = 32;
constexpr int TCAP    = 15;           // LDS triangle capacity (tiles); nwa=15 on bench data
constexpr int NLOW    = TCAP * (TCAP - 1) / 2;     // 105 strict-lower segments
constexpr int ROWPAD  = 1856;         // padded col dim (mult of 64, >= 1805)
constexpr int SOA_STRIDE = ROWPAD;
constexpr int SOA_ARR    = 8 * SOA_STRIDE;
// ws layout (bytes)
constexpr size_t WS_COUNT = 0;        // 4 ints: prop, corr, total, done
constexpr size_t WS_M     = 64;       // 8 ints
constexpr size_t WS_SOA   = 256;      // sorted SoA: 6 * SOA_ARR floats = 356,352 B
constexpr size_t WS_SUP   = 360448;   // supC region: 8*32*ROWPAD*8 = 3,801,088 B
// temporaries INSIDE the supC region (overwritten after k_rank):
constexpr size_t WS_UBOX  = WS_SUP;              // unsorted SoA, 356,352 B (supC b0 rows 0..11)
constexpr size_t WS_KEY   = WS_SUP + (1u << 20); // keys, 131,072 B (clear of supD rows)
// supD (row-oriented diag words) lives in supC row 31 of each batch: exactly 1856 u64
}

__device__ __constant__ float d_anchw[NA] = {1.3221f, 3.19275f, 5.05587f, 9.47112f, 11.2364f};
__device__ __constant__ float d_anchh[NA] = {1.73145f, 4.00944f, 8.09892f, 4.84053f, 10.0071f};

// uniform-index 64-bit readlane
__device__ inline unsigned long long rdlane64(unsigned long long v, int l) {
    unsigned lo = (unsigned)__builtin_amdgcn_readlane((int)(unsigned)(v & 0xffffffffull), l);
    unsigned hi = (unsigned)__builtin_amdgcn_readlane((int)(unsigned)(v >> 32), l);
    return ((unsigned long long)hi << 32) | lo;
}

// ---- K1a: decode -> unsorted SoA + sort keys + M count (verified R11) ----
__global__ __launch_bounds__(256, 1) void k_decode(
    const float* __restrict__ net, float* __restrict__ ubox,
    unsigned long long* __restrict__ keyg, int* __restrict__ Marr,
    int* __restrict__ counters)
{
    __shared__ int sM;
    const int b = blockIdx.x, tid = threadIdx.x, lane = tid & 63;
    const float* op = net + (size_t)b * (NA * 25 * NCELL);
    if (tid == 0) sM = 0;
    if (b == 0 && tid < 4) counters[tid] = 0;
    __syncthreads();

    int cnt = 0;
    for (int n = tid; n < NBOX; n += 256) {
        int a = n / NCELL;
        int r = n - a * NCELL;
        int y = r / 19;
        int x = r - y * 19;
        int base = a * 25 * NCELL + r;
        float t0 = op[base];
        float t1 = op[base + 1 * NCELL];
        float t2 = op[base + 2 * NCELL];
        float t3 = op[base + 3 * NCELL];
        float t4 = op[base + 4 * NCELL];
        float cx = (1.0f / (1.0f + expf(-t0)) + (float)x) / 19.0f;
        float cy = (1.0f / (1.0f + expf(-t1)) + (float)y) / 19.0f;
        float bw = expf(t2) * (d_anchw[a] / 19.0f);
        float bh = expf(t3) * (d_anchh[a] / 19.0f);
        float det = 1.0f / (1.0f + expf(-t4));
        keyg[b * KPAD + n] = ((unsigned long long)(~__float_as_uint(det)) << 32) | (unsigned)n;
        ubox[0 * SOA_ARR + b * SOA_STRIDE + n] = cx - 0.5f * bw;
        ubox[1 * SOA_ARR + b * SOA_STRIDE + n] = cy - 0.5f * bh;
        ubox[2 * SOA_ARR + b * SOA_STRIDE + n] = cx + 0.5f * bw;
        ubox[3 * SOA_ARR + b * SOA_STRIDE + n] = cy + 0.5f * bh;
        ubox[4 * SOA_ARR + b * SOA_STRIDE + n] = bw;
        ubox[5 * SOA_ARR + b * SOA_STRIDE + n] = bh;
        cnt += (det > CONF_T) ? 1 : 0;
    }
    for (int n = NBOX + tid; n < KPAD; n += 256) keyg[b * KPAD + n] = ~0ull;
    for (int d = 32; d > 0; d >>= 1) cnt += __shfl_down(cnt, d, 64);
    if (lane == 0) atomicAdd(&sM, cnt);
    __syncthreads();
    if (tid == 0) Marr[b] = sM;
}

// ---- K1b: parallel rank sort (verified R11) ----
__global__ __launch_bounds__(256, 1) void k_rank(
    const unsigned long long* __restrict__ keyg, const float* __restrict__ ubox,
    float* __restrict__ soa)
{
    __shared__ unsigned long long lk[KPAD];      // 16 KB
    const int blk = blockIdx.x, tid = threadIdx.x;
    const int b = blk & 7, wv = tid >> 6, lane = tid & 63;
    for (int i = tid; i < KPAD; i += 256) lk[i] = keyg[b * KPAD + i];
    __syncthreads();

    const int base = (blk >> 3) * 16 + wv * 4;
    unsigned long long kp[4];
    int cnt[4] = {0, 0, 0, 0};
    #pragma unroll
    for (int x = 0; x < 4; ++x) {
        int p = base + x;
        kp[x] = (p < NBOX) ? lk[p] : 0ull;
    }
    for (int c = 0; c < KPAD / 64; ++c) {
        unsigned long long q = lk[(c << 6) + lane];
        #pragma unroll
        for (int x = 0; x < 4; ++x)
            cnt[x] += __popcll(__ballot(q < kp[x]));
    }
    #pragma unroll
    for (int x = 0; x < 4; ++x) {
        int p = base + x;
        if (p < NBOX && lane < 6) {
            float v = ubox[lane * SOA_ARR + b * SOA_STRIDE + p];
            soa[lane * SOA_ARR + b * SOA_STRIDE + cnt[x]] = v;
        }
    }
}

// ---- K2: column-oriented suppression words (verified R10/R11) ----
__global__ __launch_bounds__(256) void k_iou_colT(
    const float* __restrict__ soa, const int* __restrict__ Marr,
    unsigned long long* __restrict__ supC)
{
    const int blk  = blockIdx.x;
    const int b    = blk & 7;
    const int lane = threadIdx.x & 63;
    const int j    = (blk >> 3) * 4 + (threadIdx.x >> 6);
    const int M = Marr[b];
    if (j >= M) return;
    const float* X1 = soa + 0 * SOA_ARR + b * SOA_STRIDE;
    const float* Y1 = soa + 1 * SOA_ARR + b * SOA_STRIDE;
    const float* X2 = soa + 2 * SOA_ARR + b * SOA_STRIDE;
    const float* Y2 = soa + 3 * SOA_ARR + b * SOA_STRIDE;
    const float* Wd = soa + 4 * SOA_ARR + b * SOA_STRIDE;
    const float* Hd = soa + 5 * SOA_ARR + b * SOA_STRIDE;
    const float bx1 = X1[j], by1 = Y1[j], bx2 = X2[j], by2 = Y2[j];
    const float bw = Wd[j], bh = Hd[j], barea = bw * bh;
    const int jw = j >> 6;
    unsigned long long* outp = supC + (size_t)b * 32 * ROWPAD + j;
    for (int t = 0; t <= jw; ++t) {
        int i = (t << 6) + lane;
        float ax1 = X1[i], ay1 = Y1[i], ax2 = X2[i], ay2 = Y2[i];
        float aw = Wd[i], ah = Hd[i];
        bool pred = false;
        if (i < j) {
            float uw = fmaxf(ax2, bx2) - fminf(ax1, bx1);
            float uh = fmaxf(ay2, by2) - fminf(ay1, by1);
            float cw = aw + bw - uw;
            float ch = ah + bh - uh;
            if (cw > 0.0f && ch > 0.0f) {
                float ca = cw * ch;
                float ua = aw * ah + barea - ca;
                pred = ca > NMS_T * ua;
            }
        }
        unsigned long long m = __ballot(pred);
        if (lane == 0) outp[(size_t)t * ROWPAD] = m;
    }
}

// ---- K2b: row-oriented DIAG words -> supC row 31 (supD[b][i], i=0..1855).
// supD[b][t*64+r] bit c = "row t*64+r suppresses col t*64+c" (r<c). ----
__global__ __launch_bounds__(256) void k_diagT(
    const float* __restrict__ soa, const int* __restrict__ Marr,
    unsigned long long* __restrict__ supC)
{
    const int blk = blockIdx.x;
    const int b   = blk & 7;
    const int t   = blk >> 3;                   // tile
    const int wv  = threadIdx.x >> 6, lane = threadIdx.x & 63;
    const int M = Marr[b];
    if ((t << 6) >= M) return;
    const float* X1 = soa + 0 * SOA_ARR + b * SOA_STRIDE;
    const float* Y1 = soa + 1 * SOA_ARR + b * SOA_STRIDE;
    const float* X2 = soa + 2 * SOA_ARR + b * SOA_STRIDE;
    const float* Y2 = soa + 3 * SOA_ARR + b * SOA_STRIDE;
    const float* Wd = soa + 4 * SOA_ARR + b * SOA_STRIDE;
    const float* Hd = soa + 5 * SOA_ARR + b * SOA_STRIDE;
    const int j = (t << 6) + lane;              // col (per lane), < ROWPAD
    const float cx1 = X1[j], cy1 = Y1[j], cx2 = X2[j], cy2 = Y2[j];
    const float cw0 = Wd[j], ch0 = Hd[j];
    unsigned long long* supD = supC + ((size_t)b * 32 + 31) * ROWPAD;
    for (int k = 0; k < 16; ++k) {
        int i = (t << 6) + (wv << 4) + k;       // row (wave-uniform)
        float rx1 = X1[i], ry1 = Y1[i], rx2 = X2[i], ry2 = Y2[i];
        float rw = Wd[i], rh = Hd[i], rarea = rw * rh;
        bool pred = false;
        if (i < j && j < M) {
            float uw = fmaxf(rx2, cx2) - fminf(rx1, cx1);
            float uh = fmaxf(ry2, cy2) - fminf(ry1, cy1);
            float cw = rw + cw0 - uw;
            float ch = rh + ch0 - uh;
            if (cw > 0.0f && ch > 0.0f) {
                float ca = cw * ch;
                float ua = rarea + cw0 * ch0 - ca;
                pred = ca > NMS_T * ua;
            }
        }
        unsigned long long m = __ballot(pred);
        if (lane == 0) supD[i] = m;
    }
}

// ---- K3: pull-model NMS. Wave 0: scalar readlane diag sweep + urgent term.
// Waves 1-7: 1-ballot lazy updates of owned words. Then compact kept boxes
// into LDS (aliasing tri) and GT-match over ~K/64 chunks. ----
__global__ __launch_bounds__(512, 1) void k_sweep5(
    const float* __restrict__ soa, const float* __restrict__ tgt,
    const int* __restrict__ Marr, const unsigned long long* __restrict__ supC,
    int* __restrict__ counters, float* __restrict__ out)
{
    __shared__ unsigned long long tri[(NLOW + TCAP) * 64];   // 61,440 B
    __shared__ unsigned long long rmw[NWMAX], keepw[NWMAX];
    __shared__ int offs[NWMAX];
    __shared__ int sNV, sCorr, sProp, sK;
    const int b = blockIdx.x, tid = threadIdx.x;
    const int wv = tid >> 6, lane = tid & 63;
    const int M = Marr[b];
    const int nwa = (M + 63) >> 6;
    const unsigned long long* sb = supC + (size_t)b * 32 * ROWPAD;
    const unsigned long long* supD = sb + (size_t)31 * ROWPAD;

    if (tid < NWMAX) { rmw[tid] = 0ull; keepw[tid] = 0ull; offs[tid] = 0; }
    if (tid == 0) { sCorr = 0; sProp = 0; sK = 0; sNV = 0; }

    // stage strict-lower triangle + diagT into LDS
    const int tcap = (nwa < TCAP) ? nwa : TCAP;
    const int nlow = tcap * (tcap - 1) / 2;
    for (int s = wv; s < nlow + tcap; s += 8) {
        if (s < nlow) {
            int w = 1;
            while ((w * (w + 1)) / 2 <= s) ++w;
            int r = s - w * (w - 1) / 2;
            tri[s * 64 + lane] = sb[(size_t)r * ROWPAD + (w << 6) + lane];
        } else {
            int t = s - nlow;
            tri[(NLOW + t) * 64 + lane] = supD[(t << 6) + lane];
        }
    }
    if (wv == 1) {       // GT count via ballot (first row with cx==0)
        float cxv = (lane < TMAX) ? tgt[b * 250 + lane * 5 + 1] : 0.0f;
        unsigned long long bm = __ballot(cxv != 0.0f);
        unsigned long long inv = (~bm) & ((1ull << TMAX) - 1);
        if (lane == 0) sNV = inv ? (__ffsll((long long)inv) - 1) : TMAX;
    }

    // owned words for lazy updates: w in [2, nwa), owner = 1 + (w-2) % 7
    int ow[5]; int now = 0;
    if (wv >= 1) {
        for (int w = 2 + (wv - 1); w < nwa && now < 5; w += 7) ow[now++] = w;
    }
    __syncthreads();

    unsigned long long urgent = 0;
    int pcTot = 0;
    unsigned long long diagv = 0;
    if (wv == 0 && nwa > 0)
        diagv = (0 < tcap) ? tri[NLOW * 64 + lane] : supD[lane];

    for (int t = 0; t < nwa; ++t) {
        if (wv == 0) {
            // scalar greedy sweep for tile t (uniform readlane chain, no ballots)
            unsigned long long rm = rmw[t] | urgent;
            int rem = M - (t << 6);
            unsigned long long vm = (rem >= 64) ? ~0ull : ((1ull << rem) - 1ull);
            unsigned long long live = vm & ~rm;
            while (live) {
                int i = __ffsll((long long)live) - 1;           // uniform
                unsigned long long w = rdlane64(diagv, i);      // row i's diag word
                rm |= w;
                live &= ~w;
                live &= ~(1ull << i);
            }
            unsigned long long kp = vm & ~rm;                   // uniform
            pcTot += __popcll(kp);
            if (lane == 0) keepw[t] = kp;
            // urgent: tile t kept rows -> word t+1 (colword seg (t+1, t))
            if (t + 1 < nwa) {
                unsigned long long q = (t + 1 < tcap)
                    ? tri[((t + 1) * t / 2 + t) * 64 + lane]
                    : sb[(size_t)t * ROWPAD + ((t + 1) << 6) + lane];
                urgent = __ballot((q & kp) != 0ull);
                // prefetch next diag
                diagv = (t + 1 < tcap) ? tri[(NLOW + t + 1) * 64 + lane]
                                       : supD[((t + 1) << 6) + lane];
            }
        } else if (t >= 1) {
            // lazy: apply keepw[t-1] to owned words w >= t+1 (one ballot each)
            unsigned long long km = keepw[t - 1];               // LDS broadcast
            #pragma unroll
            for (int x = 0; x < 5; ++x) {
                if (x < now) {
                    int w = ow[x];
                    if (w >= t + 1) {
                        unsigned long long q = (w < tcap)
                            ? tri[(w * (w - 1) / 2 + (t - 1)) * 64 + lane]
                            : sb[(size_t)(t - 1) * ROWPAD + (w << 6) + lane];
                        unsigned long long hit = __ballot((q & km) != 0ull);
                        if (lane == 0 && hit) rmw[w] |= hit;    // word-exclusive
                    }
                }
            }
        }
        __syncthreads();
    }

    // prefix offsets + total K (wave 0)
    if (wv == 0) {
        int pc = (lane < nwa) ? __popcll(keepw[lane]) : 0;
        int inc = pc;
        for (int d = 1; d < 32; d <<= 1) {
            int v = __shfl_up(inc, d, 64);
            if (lane >= d) inc += v;
        }
        if (lane < nwa) offs[lane] = inc - pc;
        if (nwa > 0 && lane == nwa - 1) sK = inc;
        if (lane == 0) sProp = pcTot;
    }
    __syncthreads();

    // compact kept boxes from global SoA into LDS (aliases tri: 6*2048 floats)
    float* cb = reinterpret_cast<float*>(tri);
    const float* X1 = soa + 0 * SOA_ARR + b * SOA_STRIDE;
    const float* Y1 = soa + 1 * SOA_ARR + b * SOA_STRIDE;
    const float* X2 = soa + 2 * SOA_ARR + b * SOA_STRIDE;
    const float* Y2 = soa + 3 * SOA_ARR + b * SOA_STRIDE;
    const float* Wd = soa + 4 * SOA_ARR + b * SOA_STRIDE;
    const float* Hd = soa + 5 * SOA_ARR + b * SOA_STRIDE;
    for (int j = tid; j < M; j += 512) {
        int w = j >> 6;
        unsigned long long kw = keepw[w];
        if ((kw >> (j & 63)) & 1ull) {
            int pos = offs[w] + __popcll(kw & ((1ull << (j & 63)) - 1ull));
            cb[0 * 2048 + pos] = X1[j];
            cb[1 * 2048 + pos] = Y1[j];
            cb[2 * 2048 + pos] = X2[j];
            cb[3 * 2048 + pos] = Y2[j];
            cb[4 * 2048 + pos] = Wd[j];
            cb[5 * 2048 + pos] = Hd[j];
        }
    }
    __syncthreads();

    // GT matching over K compacted boxes (LDS), 8 waves
    const int K = sK;
    const int nv = sNV;
    for (int t = wv; t < nv; t += 8) {
        const float* g = tgt + b * 250 + t * 5;
        float gcx = g[1], gcy = g[2], gw = g[3], gh = g[4];
        float gx1 = gcx - 0.5f * gw, gx2 = gcx + 0.5f * gw;
        float gy1 = gcy - 0.5f * gh, gy2 = gcy + 0.5f * gh;
        float garea = gw * gh;
        float best = 0.0f;
        for (int j0 = 0; j0 < K; j0 += 64) {
            int j = j0 + lane;
            bool ok = j < K;
            int js = ok ? j : 0;
            float bw = cb[4 * 2048 + js], bh = cb[5 * 2048 + js];
            float uw = fmaxf(gx2, cb[2 * 2048 + js]) - fminf(gx1, cb[0 * 2048 + js]);
            float uh = fmaxf(gy2, cb[3 * 2048 + js]) - fminf(gy1, cb[1 * 2048 + js]);
            float cww = gw + bw - uw, chh = gh + bh - uh;
            float ca = (cww > 0.0f && chh > 0.0f) ? cww * chh : 0.0f;
            float ua = garea + bw * bh - ca;
            float iou = ca / ua;
            best = fmaxf(best, ok ? iou : 0.0f);
        }
        for (int d = 32; d > 0; d >>= 1) best = fmaxf(best, __shfl_down(best, d, 64));
        if (lane == 0 && best > IOU_T) atomicAdd(&sCorr, 1);
    }
    __syncthreads();

    if (tid == 0) {
        atomicAdd(counters + 0, sProp);
        atomicAdd(counters + 1, sCorr);
        atomicAdd(counters + 2, sNV);
        __threadfence();
        int done = atomicAdd(counters + 3, 1);
        if (done == 7) {
            float prop  = (float)atomicAdd(counters + 0, 0);
            float corr  = (float)atomicAdd(counters + 1, 0);
            float total = (float)atomicAdd(counters + 2, 0);
            float prec = corr / (prop + 1e-6f);
            float rec  = corr / (total + 1e-6f);
            float fs   = 2.0f * prec * rec / (prec + rec + 1e-6f);
            out[0] = total;
            out[1] = prop;
            out[2] = corr;
            out[3] = prec;
            out[4] = rec;
            out[5] = fs;
        }
    }
}

extern "C" void kernel_launch(void* const* d_in, const int* in_sizes, int n_in,
                              void* d_out, int out_size, void* d_ws, size_t ws_size,
                              hipStream_t stream) {
    const float* net = (const float*)d_in[0];   // [8,125,19,19] f32
    const float* tgt = (const float*)d_in[1];   // [8,250] f32
    char* ws = (char*)d_ws;
    int* counters = (int*)(ws + WS_COUNT);
    int* Marr     = (int*)(ws + WS_M);
    float* soa    = (float*)(ws + WS_SOA);
    float* ubox   = (float*)(ws + WS_UBOX);
    unsigned long long* keyg = (unsigned long long*)(ws + WS_KEY);
    unsigned long long* supC = (unsigned long long*)(ws + WS_SUP);

    k_decode<<<8, 256, 0, stream>>>(net, ubox, keyg, Marr, counters);
    k_rank<<<113 * 8, 256, 0, stream>>>(keyg, ubox, soa);
    k_iou_colT<<<452 * 8, 256, 0, stream>>>(soa, Marr, supC);
    k_diagT<<<29 * 8, 256, 0, stream>>>(soa, Marr, supC);
    k_sweep5<<<8, 512, 0, stream>>>(soa, tgt, Marr, supC, counters, (float*)d_out);
}